// Round 1
// 2282.758 us; speedup vs baseline: 1.0511x; 1.0511x over previous
//
#include <hip/hip_runtime.h>
#include <hip/hip_bf16.h>
#include <math.h>

// Problem constants
#define NBATCH 64
#define TT 101
#define TM 100     // T-1
#define VV 8000
#define HH 512
#define H4 2048
#define EPSBN 1e-5f

typedef __attribute__((ext_vector_type(8))) short short8;   // 8 bf16 (4 VGPRs) MFMA A/B frag
typedef __attribute__((ext_vector_type(4))) float floatx4;  // MFMA C/D frag
typedef unsigned short bfraw;                               // raw bf16 bits

__device__ __forceinline__ bfraw f2b(float f) {
  __hip_bfloat16 h = __float2bfloat16(f);
  return __builtin_bit_cast(bfraw, h);
}
__device__ __forceinline__ float sigm(float x) { return 1.f / (1.f + expf(-x)); }

// Agent-coherent (sc1) helpers: per-access coherence at L3, NO cache-wide
// inv/wb fences. Keeps read-only data (X1, masks, gamma/beta, weights) hot
// in L2 across recurrent steps.
__device__ __forceinline__ short8 ld16_coh(const bfraw* p) {
  union { unsigned long long u[2]; short8 v; } r;
  r.u[0] = __hip_atomic_load((const unsigned long long*)p, __ATOMIC_RELAXED,
                             __HIP_MEMORY_SCOPE_AGENT);
  r.u[1] = __hip_atomic_load((const unsigned long long*)p + 1, __ATOMIC_RELAXED,
                             __HIP_MEMORY_SCOPE_AGENT);
  return r.v;
}
__device__ __forceinline__ void st_u32_coh(bfraw* p, unsigned v) {
  __hip_atomic_store((unsigned*)p, v, __ATOMIC_RELAXED, __HIP_MEMORY_SCOPE_AGENT);
}
__device__ __forceinline__ void wait_ge(unsigned* p, unsigned target) {
  while (__hip_atomic_load(p, __ATOMIC_RELAXED, __HIP_MEMORY_SCOPE_AGENT) < target)
    __builtin_amdgcn_s_sleep(2);
}
// combined poll: one loop, both flags in flight per iteration (one RT chain)
__device__ __forceinline__ void wait_both(unsigned* p1, unsigned n1,
                                          unsigned* p2, unsigned n2) {
  for (;;) {
    unsigned a = __hip_atomic_load(p1, __ATOMIC_RELAXED, __HIP_MEMORY_SCOPE_AGENT);
    unsigned b = __hip_atomic_load(p2, __ATOMIC_RELAXED, __HIP_MEMORY_SCOPE_AGENT);
    if (a >= n1 && b >= n2) break;
    __builtin_amdgcn_s_sleep(2);
  }
}

// ---------------- workspace layout (bytes) ----------------
#define OFF_XE    0UL                       // [6400][512] bf16 (t-major embeddings)
#define OFF_X1    6553600UL                 // [6400][2048] f32 (x@Wih1^T + b1, t-major)
#define OFF_W1I   58982400UL                // bf16 weights
#define OFF_W1H   61079552UL
#define OFF_W2I   63176704UL
#define OFF_W2H   65273856UL
#define OFF_W3I   67371008UL
#define OFF_W3H   69468160UL
#define OFF_WDB   71565312UL                // Wd bf16 [8000][512]
#define OFF_OUT1  79757312UL                // [100][64][512] bf16
#define OFF_OUT2  86310912UL
#define OFF_H3O   92864512UL                // [64][100][512] bf16 (b-major for decoder)
#define OFF_HST   99418112UL                // [3][2][64][512] bf16 h-state double buffer
#define OFF_CST   100204544UL               // [3][64][512] f32 c-state
#define OFF_SYNC  100597760UL               // lossacc
#define OFF_DONE  100597824UL               // [3][100] u32 done counters
#define OFF_PMAX  100599040UL               // [6400][125] f32
#define OFF_PSUM  103799040UL
#define OFF_TLG   106999040UL               // [6400] f32 target logits

// ---------------- small kernels ----------------
__global__ void k_zero(unsigned* p, int n) {
  int i = blockIdx.x * 256 + threadIdx.x;
  if (i < n) p[i] = 0u;
}

__global__ void k_embed(const int* __restrict__ x, const float* __restrict__ emb,
                        bfraw* __restrict__ xe) {
  int t = blockIdx.x >> 6, b = blockIdx.x & 63;
  int idx = x[b * TT + t];
  const float* src = emb + (size_t)idx * HH;
  bfraw* dst = xe + (size_t)blockIdx.x * HH;
  for (int e = threadIdx.x; e < HH; e += 256) dst[e] = f2b(src[e]);
}

__global__ void k_cast(const float* __restrict__ s, bfraw* __restrict__ d, int n) {
  int i = blockIdx.x * 256 + threadIdx.x;
  if (i < n) d[i] = f2b(s[i]);
}

// ---------------- layer-1 input GEMM: X1 = xe @ Wih1^T + b1 ----------------
__global__ __launch_bounds__(256) void k_gemm_x1(const bfraw* __restrict__ A,
                                                 const bfraw* __restrict__ Bw,
                                                 const float* __restrict__ bias,
                                                 float* __restrict__ X1) {
  int nb = blockIdx.x, mb = blockIdx.y;   // N-block (of 2048/64=32), M-block (=t, 100)
  int tid = threadIdx.x, lane = tid & 63, wv = tid >> 6;
  int l15 = lane & 15, lq = lane >> 4;
  int m0 = mb * 64, n0 = nb * 64;
  floatx4 acc[4];
  for (int nt = 0; nt < 4; nt++) {
    float bv = bias[n0 + nt * 16 + l15];
    floatx4 t = {bv, bv, bv, bv};
    acc[nt] = t;
  }
  int arow = m0 + wv * 16 + l15;
  for (int ks = 0; ks < 16; ++ks) {
    int k = ks * 32 + lq * 8;
    short8 a = *(const short8*)&A[(size_t)arow * HH + k];
#pragma unroll
    for (int nt = 0; nt < 4; nt++) {
      short8 b = *(const short8*)&Bw[(size_t)(n0 + nt * 16 + l15) * HH + k];
      acc[nt] = __builtin_amdgcn_mfma_f32_16x16x32_bf16(a, b, acc[nt], 0, 0, 0);
    }
  }
#pragma unroll
  for (int nt = 0; nt < 4; nt++)
#pragma unroll
    for (int q = 0; q < 4; q++) {
      int m = m0 + wv * 16 + lq * 4 + q;
      X1[(size_t)m * H4 + n0 + nt * 16 + l15] = acc[nt][q];
    }
}

// ---------------- persistent recurrent kernel ----------------
// 160 blocks: [0,32)=layer1 (16 h-cols each), [32,96)=layer2 (8 cols), [96,160)=layer3 (8 cols).
// No grid barrier: per-layer-per-t done counters; cross-block data via sc1
// (agent-scope relaxed atomic) loads/stores so no L2 invalidates are needed.
// Round 3: coherent h/x loads are BATCH-STAGED into register arrays (issued
// back-to-back, one L3 latency) instead of interleaved one-at-a-time with
// MFMAs (16-32 serialized L3 round trips per step — the measured 15 us/step).
__global__ __launch_bounds__(256, 1) void k_recurrent(
    const float* __restrict__ X1,
    const bfraw* __restrict__ w1h, const bfraw* __restrict__ w2i, const bfraw* __restrict__ w2h,
    const bfraw* __restrict__ w3i, const bfraw* __restrict__ w3h,
    const float* __restrict__ b2, const float* __restrict__ b3,
    const float* __restrict__ g1, const float* __restrict__ be1, const float* __restrict__ mk1,
    const float* __restrict__ g2, const float* __restrict__ be2, const float* __restrict__ mk2,
    const float* __restrict__ g3, const float* __restrict__ be3, const float* __restrict__ mk3,
    bfraw* __restrict__ out1, bfraw* __restrict__ out2, bfraw* __restrict__ h3out,
    bfraw* __restrict__ hst, float* __restrict__ cst,
    unsigned* done) {
  __shared__ __align__(16) bfraw wlds[64 * 520];  // weight slice, row pad +8 bf16
  __shared__ __align__(16) float gd[64 * 65];     // gate dump / h buffer
  __shared__ float stats[32];                     // per-col (mu, rstd)

  const int bid = blockIdx.x, tid = threadIdx.x;
  const int lane = tid & 63, wv = tid >> 6;
  const int l15 = lane & 15, lq = lane >> 4;

  int layer, cshift, j0;
  if (bid < 32)       { layer = 0; cshift = 4; j0 = bid << 4; }
  else if (bid < 96)  { layer = 1; cshift = 3; j0 = (bid - 32) << 3; }
  else                { layer = 2; cshift = 3; j0 = (bid - 96) << 3; }
  const int cols = 1 << cshift;
  const int NT = (layer == 0) ? 4 : 2;
  const int gstride = 4 * cols + 1;

  const bfraw* wih = (layer == 1) ? w2i : w3i;
  const bfraw* whh = (layer == 0) ? w1h : ((layer == 1) ? w2h : w3h);

  // Preload weight slice into LDS. Layer1: 64 rows of Whh1 (r=g*16+jj).
  // Layer2/3: rows 0-31 = Wih (r=g*8+jj), rows 32-63 = Whh.
  if (layer == 0) {
    for (int r = wv * 16; r < wv * 16 + 16; ++r) {
      int g = r >> 4, jj = r & 15;
      const bfraw* src = whh + (size_t)(g * HH + j0 + jj) * HH;
      *(short8*)&wlds[r * 520 + lane * 8] = *(const short8*)&src[lane * 8];
    }
  } else {
    for (int r2 = wv * 16; r2 < wv * 16 + 16; ++r2) {
      int mat = r2 >> 5, r = r2 & 31;
      int g = r >> 3, jj = r & 7;
      const bfraw* src = (mat ? whh : wih) + (size_t)(g * HH + j0 + jj) * HH;
      *(short8*)&wlds[r2 * 520 + lane * 8] = *(const short8*)&src[lane * 8];
    }
  }
  __syncthreads();

  const float* bb  = (layer == 1) ? b2 : b3;
  const float* gam = (layer == 0) ? g1 : ((layer == 1) ? g2 : g3);
  const float* bet = (layer == 0) ? be1 : ((layer == 1) ? be2 : be3);
  const float* msk = (layer == 0) ? mk1 : ((layer == 1) ? mk2 : mk3);
  bfraw* hbase = hst + (size_t)layer * 2 * NBATCH * HH;
  float* myc = cst + (size_t)layer * NBATCH * HH;

  const unsigned nprev = (layer == 1) ? 32u : 64u;  // producer block count of layer-1
  const unsigned nself = (layer == 0) ? 32u : 64u;
  unsigned* dprev = done + (layer - 1) * TM;        // only used if layer>0
  unsigned* dself = done + layer * TM;

  for (int t = 0; t < TM; ++t) {
    const bfraw* hr = hbase + (size_t)(t & 1) * NBATCH * HH;       // read parity
    bfraw* hw = hbase + (size_t)((t + 1) & 1) * NBATCH * HH;       // write parity
    const bfraw* xin = ((layer == 1) ? out1 : out2) + (size_t)t * NBATCH * HH;

    // ---- acc init: recurrence-independent, issued BEFORE the poll so the
    // X1 slice streams in while thread 0 spins on the done flags ----
    floatx4 acc[4];
    if (layer == 0) {
      const float* xrow = X1 + (size_t)t * NBATCH * H4;
      int rbase = wv * 16 + lq * 4;
#pragma unroll
      for (int nt = 0; nt < 4; nt++) {
        int colg = nt * HH + j0 + l15;
        acc[nt][0] = xrow[(rbase + 0) * H4 + colg];
        acc[nt][1] = xrow[(rbase + 1) * H4 + colg];
        acc[nt][2] = xrow[(rbase + 2) * H4 + colg];
        acc[nt][3] = xrow[(rbase + 3) * H4 + colg];
      }
    } else {
      floatx4 z = {0.f, 0.f, 0.f, 0.f};
      for (int nt = 0; nt < 4; nt++) acc[nt] = z;
    }

    // ---- wait for dependencies (thread 0 polls, relaxed sc1 loads) ----
    if (tid == 0) {
      if (layer > 0) {
        if (t > 0) wait_both(dprev + t, nprev, dself + t - 1, nself);
        else       wait_ge(dprev + t, nprev);
      } else if (t > 0) {
        wait_ge(dself + t - 1, nself);
      }
    }
    __syncthreads();

    // ---- batch-stage coherent operands into registers: all loads issue
    // back-to-back (counted vmcnt on use), ONE L3 latency instead of 16-32 ----
    const int arow = wv * 16 + l15;
    short8 hg[16];
#pragma unroll
    for (int ks = 0; ks < 16; ++ks)
      hg[ks] = ld16_coh(&hr[(size_t)arow * HH + ks * 32 + lq * 8]);
    short8 xg[16];
    if (layer > 0) {
#pragma unroll
      for (int ks = 0; ks < 16; ++ks)
        xg[ks] = ld16_coh(&xin[(size_t)arow * HH + ks * 32 + lq * 8]);
    }

    if (layer == 0) {
#pragma unroll
      for (int ks = 0; ks < 16; ++ks) {
        int k = ks * 32 + lq * 8;
#pragma unroll
        for (int nt = 0; nt < 4; nt++) {
          short8 bh = *(const short8*)&wlds[(nt * 16 + l15) * 520 + k];
          acc[nt] = __builtin_amdgcn_mfma_f32_16x16x32_bf16(hg[ks], bh, acc[nt], 0, 0, 0);
        }
      }
    } else {
#pragma unroll
      for (int ks = 0; ks < 16; ++ks) {
        int k = ks * 32 + lq * 8;
#pragma unroll
        for (int nt = 0; nt < 2; nt++) {
          short8 bx = *(const short8*)&wlds[(nt * 16 + l15) * 520 + k];
          short8 bh = *(const short8*)&wlds[((32 + nt * 16) + l15) * 520 + k];
          acc[nt] = __builtin_amdgcn_mfma_f32_16x16x32_bf16(xg[ks], bx, acc[nt], 0, 0, 0);
          acc[nt] = __builtin_amdgcn_mfma_f32_16x16x32_bf16(hg[ks], bh, acc[nt], 0, 0, 0);
        }
      }
    }
    // dump gates to LDS (rows are wave-exclusive)
    {
      int rbase = wv * 16 + lq * 4;
      for (int nt = 0; nt < NT; nt++)
#pragma unroll
        for (int q = 0; q < 4; q++)
          gd[(rbase + q) * gstride + nt * 16 + l15] = acc[nt][q];
    }
    __syncthreads();
    // pointwise LSTM, paired (u32 sc1 h-state stores); h into gate-i slot
    const int half = cshift - 1;
    const int ne2 = NBATCH << half;
    for (int e = tid; e < ne2; e += 256) {
      int m = e >> half;
      int jp = (e & ((cols >> 1) - 1)) << 1;
      float hv[2];
#pragma unroll
      for (int u = 0; u < 2; u++) {
        int jj = jp + u, j = j0 + jj;
        float gi = gd[m * gstride + 0 * cols + jj];
        float gf = gd[m * gstride + 1 * cols + jj];
        float gg = gd[m * gstride + 2 * cols + jj];
        float go = gd[m * gstride + 3 * cols + jj];
        if (layer) { gi += bb[j]; gf += bb[HH + j]; gg += bb[2 * HH + j]; go += bb[3 * HH + j]; }
        float c = sigm(gf) * myc[m * HH + j] + sigm(gi) * tanhf(gg);
        float h = sigm(go) * tanhf(c);
        myc[m * HH + j] = c;
        hv[u] = h;
      }
      unsigned hpack = (unsigned)f2b(hv[0]) | ((unsigned)f2b(hv[1]) << 16);
      st_u32_coh(&hw[m * HH + j0 + jp], hpack);
      gd[m * gstride + jp] = hv[0];
      gd[m * gstride + jp + 1] = hv[1];
    }
    __syncthreads();
    // BatchNorm stats over the 64 batch rows (block-local: we own all rows)
    {
      int tpc = 256 >> cshift;                 // threads per column: 16 or 32
      int c_ = tid >> (8 - cshift), r_ = tid & (tpc - 1);
      float s1 = 0.f, s2 = 0.f;
      for (int m = r_; m < NBATCH; m += tpc) {
        float v = gd[m * gstride + c_];
        s1 += v; s2 += v * v;
      }
      for (int off = 1; off < tpc; off <<= 1) {
        s1 += __shfl_xor(s1, off);
        s2 += __shfl_xor(s2, off);
      }
      if (r_ == 0) {
        float mu = s1 * (1.f / NBATCH);
        float var = s2 * (1.f / NBATCH) - mu * mu;   // biased, as BatchNorm train
        stats[c_ * 2] = mu;
        stats[c_ * 2 + 1] = rsqrtf(var + EPSBN);
      }
    }
    __syncthreads();
    // normalize * gamma + beta, locked-dropout mask, write layer output (paired)
    for (int e = tid; e < ne2; e += 256) {
      int m = e >> half;
      int jp = (e & ((cols >> 1) - 1)) << 1;
      float ov[2];
#pragma unroll
      for (int u = 0; u < 2; u++) {
        int jj = jp + u, j = j0 + jj;
        float h = gd[m * gstride + jj];
        ov[u] = (gam[j] * ((h - stats[jj * 2]) * stats[jj * 2 + 1]) + bet[j]) * msk[m * HH + j];
      }
      unsigned opack = (unsigned)f2b(ov[0]) | ((unsigned)f2b(ov[1]) << 16);
      if (layer == 0)
        st_u32_coh(&out1[(size_t)(t * NBATCH + m) * HH + j0 + jp], opack);
      else if (layer == 1)
        st_u32_coh(&out2[(size_t)(t * NBATCH + m) * HH + j0 + jp], opack);
      else
        *(unsigned*)&h3out[((size_t)m * TM + t) * HH + j0 + jp] = opack;  // consumed post-kernel
    }
    // ---- publish: drain all this block's stores, then bump done[l][t] ----
    __builtin_amdgcn_s_waitcnt(0);   // vmcnt(0) lgkmcnt(0) expcnt(0) per wave
    __syncthreads();
    if (tid == 0)
      __hip_atomic_fetch_add(dself + t, 1u, __ATOMIC_RELAXED, __HIP_MEMORY_SCOPE_AGENT);
  }
}

// ---------------- decoder GEMM + fused transpose/softmax partials ----------------
__global__ __launch_bounds__(256) void k_dec(const bfraw* __restrict__ A,
                                             const bfraw* __restrict__ Bw,
                                             const float* __restrict__ bd,
                                             const int* __restrict__ x,
                                             float* __restrict__ out,
                                             float* __restrict__ pmax,
                                             float* __restrict__ psum,
                                             float* __restrict__ tlg) {
  __shared__ __align__(16) float tb[64 * 65];
  int nb = blockIdx.x, mb = blockIdx.y;   // N-block (125), M-block (100)
  int tid = threadIdx.x, lane = tid & 63, wv = tid >> 6;
  int l15 = lane & 15, lq = lane >> 4;
  int m0 = mb * 64, n0 = nb * 64;
  floatx4 acc[4];
  for (int nt = 0; nt < 4; nt++) {
    float bv = bd[n0 + nt * 16 + l15];
    floatx4 t = {bv, bv, bv, bv};
    acc[nt] = t;
  }
  int arow = m0 + wv * 16 + l15;
  for (int ks = 0; ks < 16; ++ks) {
    int k = ks * 32 + lq * 8;
    short8 a = *(const short8*)&A[(size_t)arow * HH + k];
#pragma unroll
    for (int nt = 0; nt < 4; nt++) {
      short8 b = *(const short8*)&Bw[(size_t)(n0 + nt * 16 + l15) * HH + k];
      acc[nt] = __builtin_amdgcn_mfma_f32_16x16x32_bf16(a, b, acc[nt], 0, 0, 0);
    }
  }
  // per-row (over this block's 64 cols) max and sum-of-exp partials
#pragma unroll
  for (int q = 0; q < 4; q++) {
    float mx = fmaxf(fmaxf(acc[0][q], acc[1][q]), fmaxf(acc[2][q], acc[3][q]));
    for (int off = 1; off < 16; off <<= 1) mx = fmaxf(mx, __shfl_xor(mx, off));
    float sm = expf(acc[0][q] - mx) + expf(acc[1][q] - mx) +
               expf(acc[2][q] - mx) + expf(acc[3][q] - mx);
    for (int off = 1; off < 16; off <<= 1) sm += __shfl_xor(sm, off);
    if (l15 == 0) {
      int m = m0 + wv * 16 + lq * 4 + q;
      pmax[(size_t)m * 125 + nb] = mx;
      psum[(size_t)m * 125 + nb] = sm;
    }
  }
  // stage C tile to LDS, then write out[b][v][t] t-contiguous (coalesced)
  {
    int rbase = wv * 16 + lq * 4;
#pragma unroll
    for (int nt = 0; nt < 4; nt++)
#pragma unroll
      for (int q = 0; q < 4; q++)
        tb[(rbase + q) * 65 + nt * 16 + l15] = acc[nt][q];
  }
  __syncthreads();
  int ml = tid & 63, vq = tid >> 6;
  int m = m0 + ml;              // global row, b-major: m = b*100 + t
  int b = m / TM, t = m - b * TM;
  int tgt = x[b * TT + t + 1];
  float* obase = out + (size_t)b * VV * TM + t;
  for (int i = 0; i < 16; ++i) {
    int cv = vq * 16 + i;
    int v = n0 + cv;
    float val = tb[ml * 65 + cv];
    obase[(size_t)v * TM] = val;
    if (v == tgt) tlg[m] = val;
  }
}

// ---------------- loss: combine partials, logsumexp, mean NLL ----------------
__global__ void k_loss(const float* __restrict__ pmax, const float* __restrict__ psum,
                       const float* __restrict__ tlg, float* acc) {
  int m = blockIdx.x * 4 + (threadIdx.x >> 6);
  int lane = threadIdx.x & 63;
  float mx = -3.4e38f;
  for (int i = lane; i < 125; i += 64) mx = fmaxf(mx, pmax[(size_t)m * 125 + i]);
  for (int off = 1; off < 64; off <<= 1) mx = fmaxf(mx, __shfl_xor(mx, off));
  float s = 0.f;
  for (int i = lane; i < 125; i += 64)
    s += psum[(size_t)m * 125 + i] * expf(pmax[(size_t)m * 125 + i] - mx);
  for (int off = 1; off < 64; off <<= 1) s += __shfl_xor(s, off);
  if (lane == 0) atomicAdd(acc, mx + logf(s) - tlg[m]);
}

__global__ void k_final(const float* acc, float* out) { out[0] = acc[0] * (1.f / 6400.f); }

// ---------------- host launch ----------------
extern "C" void kernel_launch(void* const* d_in, const int* in_sizes, int n_in,
                              void* d_out, int out_size, void* d_ws, size_t ws_size,
                              hipStream_t stream) {
  (void)in_sizes; (void)n_in; (void)out_size; (void)ws_size;
  const int*   x    = (const int*)  d_in[0];
  const float* emb  = (const float*)d_in[1];
  const float* Wd   = (const float*)d_in[2];
  const float* bd   = (const float*)d_in[3];
  const float* Wih1 = (const float*)d_in[4];
  const float* Whh1 = (const float*)d_in[5];
  const float* b1   = (const float*)d_in[6];
  const float* g1   = (const float*)d_in[7];
  const float* be1  = (const float*)d_in[8];
  const float* mk1  = (const float*)d_in[9];
  const float* Wih2 = (const float*)d_in[10];
  const float* Whh2 = (const float*)d_in[11];
  const float* b2   = (const float*)d_in[12];
  const float* g2   = (const float*)d_in[13];
  const float* be2  = (const float*)d_in[14];
  const float* mk2  = (const float*)d_in[15];
  const float* Wih3 = (const float*)d_in[16];
  const float* Whh3 = (const float*)d_in[17];
  const float* b3   = (const float*)d_in[18];
  const float* g3   = (const float*)d_in[19];
  const float* be3  = (const float*)d_in[20];
  const float* mk3  = (const float*)d_in[21];

  char* ws = (char*)d_ws;
  bfraw* XE   = (bfraw*)(ws + OFF_XE);
  float* X1   = (float*)(ws + OFF_X1);
  bfraw* W1I  = (bfraw*)(ws + OFF_W1I);
  bfraw* W1H  = (bfraw*)(ws + OFF_W1H);
  bfraw* W2I  = (bfraw*)(ws + OFF_W2I);
  bfraw* W2H  = (bfraw*)(ws + OFF_W2H);
  bfraw* W3I  = (bfraw*)(ws + OFF_W3I);
  bfraw* W3H  = (bfraw*)(ws + OFF_W3H);
  bfraw* WDB  = (bfraw*)(ws + OFF_WDB);
  bfraw* OUT1 = (bfraw*)(ws + OFF_OUT1);
  bfraw* OUT2 = (bfraw*)(ws + OFF_OUT2);
  bfraw* H3O  = (bfraw*)(ws + OFF_H3O);
  bfraw* HST  = (bfraw*)(ws + OFF_HST);
  float* CST  = (float*)(ws + OFF_CST);
  float* LACC = (float*)(ws + OFF_SYNC);
  unsigned* DONE = (unsigned*)(ws + OFF_DONE);
  float* PMAX = (float*)(ws + OFF_PMAX);
  float* PSUM = (float*)(ws + OFF_PSUM);
  float* TLG  = (float*)(ws + OFF_TLG);

  // zero h/c states + lossacc + done counters (ws is poisoned before every launch)
  int zwords = (int)((OFF_PMAX - OFF_HST) / 4);
  k_zero<<<(zwords + 255) / 256, 256, 0, stream>>>((unsigned*)(ws + OFF_HST), zwords);

  k_embed<<<6400, 256, 0, stream>>>(x, emb, XE);

  const int nw = H4 * HH;          // 1,048,576
  k_cast<<<(nw + 255) / 256, 256, 0, stream>>>(Wih1, W1I, nw);
  k_cast<<<(nw + 255) / 256, 256, 0, stream>>>(Whh1, W1H, nw);
  k_cast<<<(nw + 255) / 256, 256, 0, stream>>>(Wih2, W2I, nw);
  k_cast<<<(nw + 255) / 256, 256, 0, stream>>>(Whh2, W2H, nw);
  k_cast<<<(nw + 255) / 256, 256, 0, stream>>>(Wih3, W3I, nw);
  k_cast<<<(nw + 255) / 256, 256, 0, stream>>>(Whh3, W3H, nw);
  const int nwd = VV * HH;         // 4,096,000
  k_cast<<<(nwd + 255) / 256, 256, 0, stream>>>(Wd, WDB, nwd);

  k_gemm_x1<<<dim3(32, 100), 256, 0, stream>>>(XE, W1I, b1, X1);

  k_recurrent<<<160, 256, 0, stream>>>(X1, W1H, W2I, W2H, W3I, W3H, b2, b3,
                                       g1, be1, mk1, g2, be2, mk2, g3, be3, mk3,
                                       OUT1, OUT2, H3O, HST, CST, DONE);

  k_dec<<<dim3(125, 100), 256, 0, stream>>>(H3O, WDB, bd, x, ((float*)d_out) + 1,
                                            PMAX, PSUM, TLG);

  k_loss<<<1600, 256, 0, stream>>>(PMAX, PSUM, TLG, LACC);
  k_final<<<1, 1, 0, stream>>>(LACC, (float*)d_out);
}

// Round 3
// 1831.204 us; speedup vs baseline: 1.3103x; 1.2466x over previous
//
#include <hip/hip_runtime.h>
#include <hip/hip_bf16.h>
#include <math.h>

// Problem constants
#define NBATCH 64
#define TT 101
#define TM 100     // T-1
#define VV 8000
#define HH 512
#define H4 2048
#define EPSBN 1e-5f

typedef __attribute__((ext_vector_type(8))) short short8;   // 8 bf16 (4 VGPRs) MFMA A/B frag
typedef __attribute__((ext_vector_type(4))) float floatx4;  // MFMA C/D frag
typedef unsigned short bfraw;                               // raw bf16 bits

__device__ __forceinline__ bfraw f2b(float f) {
  __hip_bfloat16 h = __float2bfloat16(f);
  return __builtin_bit_cast(bfraw, h);
}
__device__ __forceinline__ float sigm(float x) { return 1.f / (1.f + expf(-x)); }

__device__ __forceinline__ void st_u32_coh(bfraw* p, unsigned v) {
  __hip_atomic_store((unsigned*)p, v, __ATOMIC_RELAXED, __HIP_MEMORY_SCOPE_AGENT);
}
__device__ __forceinline__ void wait_ge(unsigned* p, unsigned target) {
  while (__hip_atomic_load(p, __ATOMIC_RELAXED, __HIP_MEMORY_SCOPE_AGENT) < target)
    __builtin_amdgcn_s_sleep(2);
}
// combined poll: one loop, both flags in flight per iteration (one RT chain)
__device__ __forceinline__ void wait_both(unsigned* p1, unsigned n1,
                                          unsigned* p2, unsigned n2) {
  for (;;) {
    unsigned a = __hip_atomic_load(p1, __ATOMIC_RELAXED, __HIP_MEMORY_SCOPE_AGENT);
    unsigned b = __hip_atomic_load(p2, __ATOMIC_RELAXED, __HIP_MEMORY_SCOPE_AGENT);
    if (a >= n1 && b >= n2) break;
    __builtin_amdgcn_s_sleep(2);
  }
}

// Batched agent-coherent 16B loads: inline asm so hipcc CANNOT sink/serialize
// them (round-1 post-mortem: __hip_atomic_load chains were re-interleaved with
// MFMAs -> 16-32 serial L3 round trips/step; VGPR stayed 132). One base
// address, immediate offsets, all loads in flight -> ONE L3 latency.
#define GLD4(dst, base, OFFS) \
  asm volatile("global_load_dwordx4 %0, %1, off offset:" OFFS " sc1" \
               : "=&v"(dst) : "v"(base))
#define LD16(a, base) do { \
  GLD4(a[0],  base, "0");   GLD4(a[1],  base, "64");  \
  GLD4(a[2],  base, "128"); GLD4(a[3],  base, "192"); \
  GLD4(a[4],  base, "256"); GLD4(a[5],  base, "320"); \
  GLD4(a[6],  base, "384"); GLD4(a[7],  base, "448"); \
  GLD4(a[8],  base, "512"); GLD4(a[9],  base, "576"); \
  GLD4(a[10], base, "640"); GLD4(a[11], base, "704"); \
  GLD4(a[12], base, "768"); GLD4(a[13], base, "832"); \
  GLD4(a[14], base, "896"); GLD4(a[15], base, "960"); \
} while (0)

// ---------------- workspace layout (bytes) ----------------
#define OFF_XE    0UL                       // [6400][512] bf16 (t-major embeddings)
#define OFF_X1    6553600UL                 // [6400][2048] f32 (x@Wih1^T + b1, t-major)
#define OFF_W1I   58982400UL                // bf16 weights
#define OFF_W1H   61079552UL
#define OFF_W2I   63176704UL
#define OFF_W2H   65273856UL
#define OFF_W3I   67371008UL
#define OFF_W3H   69468160UL
#define OFF_WDB   71565312UL                // Wd bf16 [8000][512]
#define OFF_OUT1  79757312UL                // [100][64][512] bf16
#define OFF_OUT2  86310912UL
#define OFF_H3O   92864512UL                // [64][100][512] bf16 (b-major for decoder)
#define OFF_HST   99418112UL                // [3][2][64][512] bf16 h-state double buffer
#define OFF_ODONE 99811328UL                // [3][100] u32 out-ready counters (in HST-CST gap)
#define OFF_CST   100204544UL               // [3][64][512] f32 c-state
#define OFF_SYNC  100597760UL               // lossacc
#define OFF_DONE  100597824UL               // [3][100] u32 h-ready counters
#define OFF_PMAX  100599040UL               // [6400][125] f32
#define OFF_PSUM  103799040UL
#define OFF_TLG   106999040UL               // [6400] f32 target logits

// ---------------- small kernels ----------------
__global__ void k_zero(unsigned* p, int n) {
  int i = blockIdx.x * 256 + threadIdx.x;
  if (i < n) p[i] = 0u;
}

__global__ void k_embed(const int* __restrict__ x, const float* __restrict__ emb,
                        bfraw* __restrict__ xe) {
  int t = blockIdx.x >> 6, b = blockIdx.x & 63;
  int idx = x[b * TT + t];
  const float* src = emb + (size_t)idx * HH;
  bfraw* dst = xe + (size_t)blockIdx.x * HH;
  for (int e = threadIdx.x; e < HH; e += 256) dst[e] = f2b(src[e]);
}

__global__ void k_cast(const float* __restrict__ s, bfraw* __restrict__ d, int n) {
  int i = blockIdx.x * 256 + threadIdx.x;
  if (i < n) d[i] = f2b(s[i]);
}

// ---------------- layer-1 input GEMM: X1 = xe @ Wih1^T + b1 ----------------
__global__ __launch_bounds__(256) void k_gemm_x1(const bfraw* __restrict__ A,
                                                 const bfraw* __restrict__ Bw,
                                                 const float* __restrict__ bias,
                                                 float* __restrict__ X1) {
  int nb = blockIdx.x, mb = blockIdx.y;   // N-block (of 2048/64=32), M-block (=t, 100)
  int tid = threadIdx.x, lane = tid & 63, wv = tid >> 6;
  int l15 = lane & 15, lq = lane >> 4;
  int m0 = mb * 64, n0 = nb * 64;
  floatx4 acc[4];
  for (int nt = 0; nt < 4; nt++) {
    float bv = bias[n0 + nt * 16 + l15];
    floatx4 t = {bv, bv, bv, bv};
    acc[nt] = t;
  }
  int arow = m0 + wv * 16 + l15;
  for (int ks = 0; ks < 16; ++ks) {
    int k = ks * 32 + lq * 8;
    short8 a = *(const short8*)&A[(size_t)arow * HH + k];
#pragma unroll
    for (int nt = 0; nt < 4; nt++) {
      short8 b = *(const short8*)&Bw[(size_t)(n0 + nt * 16 + l15) * HH + k];
      acc[nt] = __builtin_amdgcn_mfma_f32_16x16x32_bf16(a, b, acc[nt], 0, 0, 0);
    }
  }
#pragma unroll
  for (int nt = 0; nt < 4; nt++)
#pragma unroll
    for (int q = 0; q < 4; q++) {
      int m = m0 + wv * 16 + lq * 4 + q;
      X1[(size_t)m * H4 + n0 + nt * 16 + l15] = acc[nt][q];
    }
}

// ---------------- persistent recurrent kernel ----------------
// 160 blocks: [0,32)=layer1 (16 h-cols each), [32,96)=layer2 (8 cols), [96,160)=layer3 (8 cols).
// No grid barrier. Two flag families:
//   hdone[l][t]: bumped right after the pointwise h-stores drain -> shortens the
//                per-layer self-recurrence loop (the throughput bound) by the
//                whole BN/normalize/out phase.
//   odone[l][t]: bumped after BN+out stores drain; waited on by layer l+1.
// Cross-block data via sc1 (agent-scope) loads/stores, no L2 invalidates.
__global__ __launch_bounds__(256, 1) void k_recurrent(
    const float* __restrict__ X1,
    const bfraw* __restrict__ w1h, const bfraw* __restrict__ w2i, const bfraw* __restrict__ w2h,
    const bfraw* __restrict__ w3i, const bfraw* __restrict__ w3h,
    const float* __restrict__ b2, const float* __restrict__ b3,
    const float* __restrict__ g1, const float* __restrict__ be1, const float* __restrict__ mk1,
    const float* __restrict__ g2, const float* __restrict__ be2, const float* __restrict__ mk2,
    const float* __restrict__ g3, const float* __restrict__ be3, const float* __restrict__ mk3,
    bfraw* __restrict__ out1, bfraw* __restrict__ out2, bfraw* __restrict__ h3out,
    bfraw* __restrict__ hst, float* __restrict__ cst,
    unsigned* hdone, unsigned* odone) {
  __shared__ __align__(16) bfraw wlds[64 * 520];  // weight slice, row pad +8 bf16
  __shared__ __align__(16) float gd[64 * 65];     // gate dump / h buffer
  __shared__ float stats[32];                     // per-col (mu, rstd)

  const int bid = blockIdx.x, tid = threadIdx.x;
  const int lane = tid & 63, wv = tid >> 6;
  const int l15 = lane & 15, lq = lane >> 4;

  int layer, cshift, j0;
  if (bid < 32)       { layer = 0; cshift = 4; j0 = bid << 4; }
  else if (bid < 96)  { layer = 1; cshift = 3; j0 = (bid - 32) << 3; }
  else                { layer = 2; cshift = 3; j0 = (bid - 96) << 3; }
  const int cols = 1 << cshift;
  const int NT = (layer == 0) ? 4 : 2;
  const int gstride = 4 * cols + 1;

  const bfraw* wih = (layer == 1) ? w2i : w3i;
  const bfraw* whh = (layer == 0) ? w1h : ((layer == 1) ? w2h : w3h);

  // Preload weight slice into LDS. Layer1: 64 rows of Whh1 (r=g*16+jj).
  // Layer2/3: rows 0-31 = Wih (r=g*8+jj), rows 32-63 = Whh.
  if (layer == 0) {
    for (int r = wv * 16; r < wv * 16 + 16; ++r) {
      int g = r >> 4, jj = r & 15;
      const bfraw* src = whh + (size_t)(g * HH + j0 + jj) * HH;
      *(short8*)&wlds[r * 520 + lane * 8] = *(const short8*)&src[lane * 8];
    }
  } else {
    for (int r2 = wv * 16; r2 < wv * 16 + 16; ++r2) {
      int mat = r2 >> 5, r = r2 & 31;
      int g = r >> 3, jj = r & 7;
      const bfraw* src = (mat ? whh : wih) + (size_t)(g * HH + j0 + jj) * HH;
      *(short8*)&wlds[r2 * 520 + lane * 8] = *(const short8*)&src[lane * 8];
    }
  }
  __syncthreads();

  const float* bb  = (layer == 1) ? b2 : b3;
  const float* gam = (layer == 0) ? g1 : ((layer == 1) ? g2 : g3);
  const float* bet = (layer == 0) ? be1 : ((layer == 1) ? be2 : be3);
  const float* msk = (layer == 0) ? mk1 : ((layer == 1) ? mk2 : mk3);
  bfraw* hbase = hst + (size_t)layer * 2 * NBATCH * HH;
  float* myc = cst + (size_t)layer * NBATCH * HH;

  const unsigned nprev = (layer == 1) ? 32u : 64u;  // producer block count
  const unsigned nself = (layer == 0) ? 32u : 64u;
  unsigned* oprev = odone + (layer - 1) * TM;       // only used if layer>0
  unsigned* hself = hdone + layer * TM;
  unsigned* oself = odone + layer * TM;

  for (int t = 0; t < TM; ++t) {
    const bfraw* hr = hbase + (size_t)(t & 1) * NBATCH * HH;       // read parity
    bfraw* hw = hbase + (size_t)((t + 1) & 1) * NBATCH * HH;       // write parity
    const bfraw* xin = ((layer == 1) ? out1 : out2) + (size_t)t * NBATCH * HH;

    // ---- acc init: recurrence-independent, issued BEFORE the poll so the
    // X1 slice streams in while thread 0 spins on the done flags ----
    floatx4 acc[4];
    if (layer == 0) {
      const float* xrow = X1 + (size_t)t * NBATCH * H4;
      int rbase = wv * 16 + lq * 4;
#pragma unroll
      for (int nt = 0; nt < 4; nt++) {
        int colg = nt * HH + j0 + l15;
        acc[nt][0] = xrow[(rbase + 0) * H4 + colg];
        acc[nt][1] = xrow[(rbase + 1) * H4 + colg];
        acc[nt][2] = xrow[(rbase + 2) * H4 + colg];
        acc[nt][3] = xrow[(rbase + 3) * H4 + colg];
      }
    } else {
      floatx4 z = {0.f, 0.f, 0.f, 0.f};
      for (int nt = 0; nt < 4; nt++) acc[nt] = z;
    }

    // ---- wait for dependencies (thread 0 polls, relaxed sc1 loads) ----
    if (tid == 0) {
      if (layer == 0) {
        if (t > 0) wait_ge(hself + t - 1, nself);
      } else {
        if (t > 0) wait_both(oprev + t, nprev, hself + t - 1, nself);
        else       wait_ge(oprev + t, nprev);
      }
    }
    __syncthreads();

    // ---- batch-issue ALL coherent operand loads (asm, one vmcnt wait) ----
    const int arow = wv * 16 + l15;
    const bfraw* ph = hr + (size_t)arow * HH + lq * 8;
    short8 hg[16];
    LD16(hg, ph);
    short8 xg[16];
    if (layer > 0) {
      const bfraw* px = xin + (size_t)arow * HH + lq * 8;
      LD16(xg, px);
    }
    asm volatile("s_waitcnt vmcnt(0)" ::: "memory");
    __builtin_amdgcn_sched_barrier(0);

    if (layer == 0) {
#pragma unroll
      for (int ks = 0; ks < 16; ++ks) {
        int k = ks * 32 + lq * 8;
#pragma unroll
        for (int nt = 0; nt < 4; nt++) {
          short8 bh = *(const short8*)&wlds[(nt * 16 + l15) * 520 + k];
          acc[nt] = __builtin_amdgcn_mfma_f32_16x16x32_bf16(hg[ks], bh, acc[nt], 0, 0, 0);
        }
      }
    } else {
#pragma unroll
      for (int ks = 0; ks < 16; ++ks) {
        int k = ks * 32 + lq * 8;
#pragma unroll
        for (int nt = 0; nt < 2; nt++) {
          short8 bx = *(const short8*)&wlds[(nt * 16 + l15) * 520 + k];
          short8 bh = *(const short8*)&wlds[((32 + nt * 16) + l15) * 520 + k];
          acc[nt] = __builtin_amdgcn_mfma_f32_16x16x32_bf16(xg[ks], bx, acc[nt], 0, 0, 0);
          acc[nt] = __builtin_amdgcn_mfma_f32_16x16x32_bf16(hg[ks], bh, acc[nt], 0, 0, 0);
        }
      }
    }
    // dump gates to LDS (rows are wave-exclusive)
    {
      int rbase = wv * 16 + lq * 4;
      for (int nt = 0; nt < NT; nt++)
#pragma unroll
        for (int q = 0; q < 4; q++)
          gd[(rbase + q) * gstride + nt * 16 + l15] = acc[nt][q];
    }
    __syncthreads();
    // pointwise LSTM, paired (u32 sc1 h-state stores); h into gate-i slot
    const int half = cshift - 1;
    const int ne2 = NBATCH << half;
    for (int e = tid; e < ne2; e += 256) {
      int m = e >> half;
      int jp = (e & ((cols >> 1) - 1)) << 1;
      float hv[2];
#pragma unroll
      for (int u = 0; u < 2; u++) {
        int jj = jp + u, j = j0 + jj;
        float gi = gd[m * gstride + 0 * cols + jj];
        float gf = gd[m * gstride + 1 * cols + jj];
        float gg = gd[m * gstride + 2 * cols + jj];
        float go = gd[m * gstride + 3 * cols + jj];
        if (layer) { gi += bb[j]; gf += bb[HH + j]; gg += bb[2 * HH + j]; go += bb[3 * HH + j]; }
        float c = sigm(gf) * myc[m * HH + j] + sigm(gi) * tanhf(gg);
        float h = sigm(go) * tanhf(c);
        myc[m * HH + j] = c;
        hv[u] = h;
      }
      unsigned hpack = (unsigned)f2b(hv[0]) | ((unsigned)f2b(hv[1]) << 16);
      st_u32_coh(&hw[m * HH + j0 + jp], hpack);
      gd[m * gstride + jp] = hv[0];
      gd[m * gstride + jp + 1] = hv[1];
    }
    // ---- publish h EARLY: self-recurrence consumers unblock before BN/out ----
    __builtin_amdgcn_s_waitcnt(0);   // drain h stores (vmcnt lgkm exp), per wave
    __syncthreads();
    if (tid == 0)
      __hip_atomic_fetch_add(hself + t, 1u, __ATOMIC_RELAXED, __HIP_MEMORY_SCOPE_AGENT);
    // BatchNorm stats over the 64 batch rows (block-local: we own all rows)
    {
      int tpc = 256 >> cshift;                 // threads per column: 16 or 32
      int c_ = tid >> (8 - cshift), r_ = tid & (tpc - 1);
      float s1 = 0.f, s2 = 0.f;
      for (int m = r_; m < NBATCH; m += tpc) {
        float v = gd[m * gstride + c_];
        s1 += v; s2 += v * v;
      }
      for (int off = 1; off < tpc; off <<= 1) {
        s1 += __shfl_xor(s1, off);
        s2 += __shfl_xor(s2, off);
      }
      if (r_ == 0) {
        float mu = s1 * (1.f / NBATCH);
        float var = s2 * (1.f / NBATCH) - mu * mu;   // biased, as BatchNorm train
        stats[c_ * 2] = mu;
        stats[c_ * 2 + 1] = rsqrtf(var + EPSBN);
      }
    }
    __syncthreads();
    // normalize * gamma + beta, locked-dropout mask, write layer output (paired)
    for (int e = tid; e < ne2; e += 256) {
      int m = e >> half;
      int jp = (e & ((cols >> 1) - 1)) << 1;
      float ov[2];
#pragma unroll
      for (int u = 0; u < 2; u++) {
        int jj = jp + u, j = j0 + jj;
        float h = gd[m * gstride + jj];
        ov[u] = (gam[j] * ((h - stats[jj * 2]) * stats[jj * 2 + 1]) + bet[j]) * msk[m * HH + j];
      }
      unsigned opack = (unsigned)f2b(ov[0]) | ((unsigned)f2b(ov[1]) << 16);
      if (layer == 0)
        st_u32_coh(&out1[(size_t)(t * NBATCH + m) * HH + j0 + jp], opack);
      else if (layer == 1)
        st_u32_coh(&out2[(size_t)(t * NBATCH + m) * HH + j0 + jp], opack);
      else
        *(unsigned*)&h3out[((size_t)m * TM + t) * HH + j0 + jp] = opack;  // consumed post-kernel
    }
    // ---- publish out (layers 0,1): drain out stores, bump odone[l][t] ----
    if (layer < 2) {
      __builtin_amdgcn_s_waitcnt(0);
      __syncthreads();
      if (tid == 0)
        __hip_atomic_fetch_add(oself + t, 1u, __ATOMIC_RELAXED, __HIP_MEMORY_SCOPE_AGENT);
    }
    // layer 2: next iteration's post-poll __syncthreads covers gd reuse;
    // h3out visibility is guaranteed by kernel completion.
  }
}

// ---------------- decoder GEMM + fused transpose/softmax partials ----------------
__global__ __launch_bounds__(256) void k_dec(const bfraw* __restrict__ A,
                                             const bfraw* __restrict__ Bw,
                                             const float* __restrict__ bd,
                                             const int* __restrict__ x,
                                             float* __restrict__ out,
                                             float* __restrict__ pmax,
                                             float* __restrict__ psum,
                                             float* __restrict__ tlg) {
  __shared__ __align__(16) float tb[64 * 65];
  int nb = blockIdx.x, mb = blockIdx.y;   // N-block (125), M-block (100)
  int tid = threadIdx.x, lane = tid & 63, wv = tid >> 6;
  int l15 = lane & 15, lq = lane >> 4;
  int m0 = mb * 64, n0 = nb * 64;
  floatx4 acc[4];
  for (int nt = 0; nt < 4; nt++) {
    float bv = bd[n0 + nt * 16 + l15];
    floatx4 t = {bv, bv, bv, bv};
    acc[nt] = t;
  }
  int arow = m0 + wv * 16 + l15;
  for (int ks = 0; ks < 16; ++ks) {
    int k = ks * 32 + lq * 8;
    short8 a = *(const short8*)&A[(size_t)arow * HH + k];
#pragma unroll
    for (int nt = 0; nt < 4; nt++) {
      short8 b = *(const short8*)&Bw[(size_t)(n0 + nt * 16 + l15) * HH + k];
      acc[nt] = __builtin_amdgcn_mfma_f32_16x16x32_bf16(a, b, acc[nt], 0, 0, 0);
    }
  }
  // per-row (over this block's 64 cols) max and sum-of-exp partials
#pragma unroll
  for (int q = 0; q < 4; q++) {
    float mx = fmaxf(fmaxf(acc[0][q], acc[1][q]), fmaxf(acc[2][q], acc[3][q]));
    for (int off = 1; off < 16; off <<= 1) mx = fmaxf(mx, __shfl_xor(mx, off));
    float sm = expf(acc[0][q] - mx) + expf(acc[1][q] - mx) +
               expf(acc[2][q] - mx) + expf(acc[3][q] - mx);
    for (int off = 1; off < 16; off <<= 1) sm += __shfl_xor(sm, off);
    if (l15 == 0) {
      int m = m0 + wv * 16 + lq * 4 + q;
      pmax[(size_t)m * 125 + nb] = mx;
      psum[(size_t)m * 125 + nb] = sm;
    }
  }
  // stage C tile to LDS, then write out[b][v][t] t-contiguous (coalesced)
  {
    int rbase = wv * 16 + lq * 4;
#pragma unroll
    for (int nt = 0; nt < 4; nt++)
#pragma unroll
      for (int q = 0; q < 4; q++)
        tb[(rbase + q) * 65 + nt * 16 + l15] = acc[nt][q];
  }
  __syncthreads();
  int ml = tid & 63, vq = tid >> 6;
  int m = m0 + ml;              // global row, b-major: m = b*100 + t
  int b = m / TM, t = m - b * TM;
  int tgt = x[b * TT + t + 1];
  float* obase = out + (size_t)b * VV * TM + t;
  for (int i = 0; i < 16; ++i) {
    int cv = vq * 16 + i;
    int v = n0 + cv;
    float val = tb[ml * 65 + cv];
    obase[(size_t)v * TM] = val;
    if (v == tgt) tlg[m] = val;
  }
}

// ---------------- loss: combine partials, logsumexp, mean NLL ----------------
__global__ void k_loss(const float* __restrict__ pmax, const float* __restrict__ psum,
                       const float* __restrict__ tlg, float* acc) {
  int m = blockIdx.x * 4 + (threadIdx.x >> 6);
  int lane = threadIdx.x & 63;
  float mx = -3.4e38f;
  for (int i = lane; i < 125; i += 64) mx = fmaxf(mx, pmax[(size_t)m * 125 + i]);
  for (int off = 1; off < 64; off <<= 1) mx = fmaxf(mx, __shfl_xor(mx, off));
  float s = 0.f;
  for (int i = lane; i < 125; i += 64)
    s += psum[(size_t)m * 125 + i] * expf(pmax[(size_t)m * 125 + i] - mx);
  for (int off = 1; off < 64; off <<= 1) s += __shfl_xor(s, off);
  if (lane == 0) atomicAdd(acc, mx + logf(s) - tlg[m]);
}

__global__ void k_final(const float* acc, float* out) { out[0] = acc[0] * (1.f / 6400.f); }

// ---------------- host launch ----------------
extern "C" void kernel_launch(void* const* d_in, const int* in_sizes, int n_in,
                              void* d_out, int out_size, void* d_ws, size_t ws_size,
                              hipStream_t stream) {
  (void)in_sizes; (void)n_in; (void)out_size; (void)ws_size;
  const int*   x    = (const int*)  d_in[0];
  const float* emb  = (const float*)d_in[1];
  const float* Wd   = (const float*)d_in[2];
  const float* bd   = (const float*)d_in[3];
  const float* Wih1 = (const float*)d_in[4];
  const float* Whh1 = (const float*)d_in[5];
  const float* b1   = (const float*)d_in[6];
  const float* g1   = (const float*)d_in[7];
  const float* be1  = (const float*)d_in[8];
  const float* mk1  = (const float*)d_in[9];
  const float* Wih2 = (const float*)d_in[10];
  const float* Whh2 = (const float*)d_in[11];
  const float* b2   = (const float*)d_in[12];
  const float* g2   = (const float*)d_in[13];
  const float* be2  = (const float*)d_in[14];
  const float* mk2  = (const float*)d_in[15];
  const float* Wih3 = (const float*)d_in[16];
  const float* Whh3 = (const float*)d_in[17];
  const float* b3   = (const float*)d_in[18];
  const float* g3   = (const float*)d_in[19];
  const float* be3  = (const float*)d_in[20];
  const float* mk3  = (const float*)d_in[21];

  char* ws = (char*)d_ws;
  bfraw* XE   = (bfraw*)(ws + OFF_XE);
  float* X1   = (float*)(ws + OFF_X1);
  bfraw* W1I  = (bfraw*)(ws + OFF_W1I);
  bfraw* W1H  = (bfraw*)(ws + OFF_W1H);
  bfraw* W2I  = (bfraw*)(ws + OFF_W2I);
  bfraw* W2H  = (bfraw*)(ws + OFF_W2H);
  bfraw* W3I  = (bfraw*)(ws + OFF_W3I);
  bfraw* W3H  = (bfraw*)(ws + OFF_W3H);
  bfraw* WDB  = (bfraw*)(ws + OFF_WDB);
  bfraw* OUT1 = (bfraw*)(ws + OFF_OUT1);
  bfraw* OUT2 = (bfraw*)(ws + OFF_OUT2);
  bfraw* H3O  = (bfraw*)(ws + OFF_H3O);
  bfraw* HST  = (bfraw*)(ws + OFF_HST);
  float* CST  = (float*)(ws + OFF_CST);
  float* LACC = (float*)(ws + OFF_SYNC);
  unsigned* HDONE = (unsigned*)(ws + OFF_DONE);
  unsigned* ODONE = (unsigned*)(ws + OFF_ODONE);
  float* PMAX = (float*)(ws + OFF_PMAX);
  float* PSUM = (float*)(ws + OFF_PSUM);
  float* TLG  = (float*)(ws + OFF_TLG);

  // zero h/c states + lossacc + done counters (ws is poisoned before every launch)
  // range [OFF_HST, OFF_PMAX) covers HST, ODONE (in the gap), CST, SYNC, HDONE
  int zwords = (int)((OFF_PMAX - OFF_HST) / 4);
  k_zero<<<(zwords + 255) / 256, 256, 0, stream>>>((unsigned*)(ws + OFF_HST), zwords);

  k_embed<<<6400, 256, 0, stream>>>(x, emb, XE);

  const int nw = H4 * HH;          // 1,048,576
  k_cast<<<(nw + 255) / 256, 256, 0, stream>>>(Wih1, W1I, nw);
  k_cast<<<(nw + 255) / 256, 256, 0, stream>>>(Whh1, W1H, nw);
  k_cast<<<(nw + 255) / 256, 256, 0, stream>>>(Wih2, W2I, nw);
  k_cast<<<(nw + 255) / 256, 256, 0, stream>>>(Whh2, W2H, nw);
  k_cast<<<(nw + 255) / 256, 256, 0, stream>>>(Wih3, W3I, nw);
  k_cast<<<(nw + 255) / 256, 256, 0, stream>>>(Whh3, W3H, nw);
  const int nwd = VV * HH;         // 4,096,000
  k_cast<<<(nwd + 255) / 256, 256, 0, stream>>>(Wd, WDB, nwd);

  k_gemm_x1<<<dim3(32, 100), 256, 0, stream>>>(XE, W1I, b1, X1);

  k_recurrent<<<160, 256, 0, stream>>>(X1, W1H, W2I, W2H, W3I, W3H, b2, b3,
                                       g1, be1, mk1, g2, be2, mk2, g3, be3, mk3,
                                       OUT1, OUT2, H3O, HST, CST, HDONE, ODONE);

  k_dec<<<dim3(125, 100), 256, 0, stream>>>(H3O, WDB, bd, x, ((float*)d_out) + 1,
                                            PMAX, PSUM, TLG);

  k_loss<<<1600, 256, 0, stream>>>(PMAX, PSUM, TLG, LACC);
  k_final<<<1, 1, 0, stream>>>(LACC, (float*)d_out);
}